// Round 6
// baseline (175.977 us; speedup 1.0000x reference)
//
#include <hip/hip_runtime.h>
#include <math.h>

typedef __bf16 bf16_t;
typedef bf16_t bf16x4 __attribute__((ext_vector_type(4)));
typedef bf16_t bf16x8 __attribute__((ext_vector_type(8)));
typedef float  f32x4  __attribute__((ext_vector_type(4)));

__device__ __forceinline__ float softplus_f(float x) {
    return (x > 20.f) ? x : log1pf(expf(x));
}

__device__ __forceinline__ float fast_rcp(float x) {
#if __has_builtin(__builtin_amdgcn_rcpf)
    return __builtin_amdgcn_rcpf(x);
#else
    return 1.0f / x;
#endif
}

// ---------------- prep: z<8 transpose+convert weights, z==8 convert activations ----------------
struct PrepArgs { const float* src[8]; const float* mu; const float* var; };

__global__ __launch_bounds__(256) void prep_kernel(PrepArgs pa, bf16_t* __restrict__ wtbase,
                                                   bf16_t* __restrict__ dmu, bf16_t* __restrict__ dvar) {
    const int t = threadIdx.x;
    if (blockIdx.z == 8) {
        const int gid = (blockIdx.y * 16 + blockIdx.x) * 256 + t;   // 0..65535
        const float* s; bf16_t* d; int off;
        if (gid < 32768) { s = pa.mu;  d = dmu;  off = gid * 8; }
        else             { s = pa.var; d = dvar; off = (gid - 32768) * 8; }
        float4 v0 = *(const float4*)(s + off);
        float4 v1 = *(const float4*)(s + off + 4);
        bf16x8 o;
        o[0] = (bf16_t)v0.x; o[1] = (bf16_t)v0.y; o[2] = (bf16_t)v0.z; o[3] = (bf16_t)v0.w;
        o[4] = (bf16_t)v1.x; o[5] = (bf16_t)v1.y; o[6] = (bf16_t)v1.z; o[7] = (bf16_t)v1.w;
        *(bf16x8*)(d + off) = o;
        return;
    }
    const int kt = blockIdx.x, nt = blockIdx.y, wm = blockIdx.z;
    const float* __restrict__ W = pa.src[wm];
    bf16_t* __restrict__ Wt = wtbase + (size_t)wm * 1048576;
    __shared__ bf16_t Ts[64][72];
    const int r0 = t >> 4, c4 = (t & 15) * 4;
#pragma unroll
    for (int rep = 0; rep < 4; ++rep) {
        const int r = r0 + rep * 16;
        const float4 v = *(const float4*)&W[(size_t)(kt * 64 + r) * 1024 + nt * 64 + c4];
        Ts[c4 + 0][r] = (bf16_t)v.x;
        Ts[c4 + 1][r] = (bf16_t)v.y;
        Ts[c4 + 2][r] = (bf16_t)v.z;
        Ts[c4 + 3][r] = (bf16_t)v.w;
    }
    __syncthreads();
#pragma unroll
    for (int rep = 0; rep < 2; ++rep) {
        const int chunk = t + rep * 256;
        const int n = chunk >> 3, kc = (chunk & 7) * 8;
        bf16x8 v = *(const bf16x8*)&Ts[n][kc];
        *(bf16x8*)&Wt[(size_t)(nt * 64 + n) * 1024 + kt * 64 + kc] = v;
    }
}

// ---------------- gemm: 64x32 tile, split-K per wave, register-prefetch pipeline ----------------
struct GemmArgs {
    const bf16_t* A[6];
    const bf16_t* Wt[6];
    const float*  bias[6];
    float*        dst[6];
    int           splus[6];
};

__global__ __launch_bounds__(256, 2) void gemm_splitk(GemmArgs args) {
    const int z = blockIdx.z;
    const bf16_t* __restrict__ A    = args.A[z];
    const bf16_t* __restrict__ Wt   = args.Wt[z];
    const float*  __restrict__ bias = args.bias[z];
    float*        __restrict__ dst  = args.dst[z];
    const int sp = args.splus[z];

    const int n_base = blockIdx.x * 32;
    const int m_base = blockIdx.y * 64;

    __shared__ __align__(16) unsigned char smem_raw[55296];
    bf16_t* stage = (bf16_t*)smem_raw;          // per wave: As 64x72 + Bs 32x72 bf16
    float*  Cr    = (float*)smem_raw;           // reduce phase: [4][64][36] fp32

    const int t = threadIdx.x;
    const int lane = t & 63;
    const int w = t >> 6;
    bf16_t* As = stage + w * 6912;
    bf16_t* Bs = As + 4608;

    const int r8 = lane >> 3, kb = lane & 7;
    const int fr = lane & 15, fq = lane >> 4, fk = fq * 8;

    const bf16_t* Ab = A  + (size_t)m_base * 1024 + w * 256 + kb * 8;
    const bf16_t* Bb = Wt + (size_t)n_base * 1024 + w * 256 + kb * 8;

    f32x4 acc[4][2] = {};

    // prefetch slice 0
    bf16x8 pa[8], pb[4];
#pragma unroll
    for (int i = 0; i < 8; ++i) pa[i] = *(const bf16x8*)(Ab + (size_t)(i * 8 + r8) * 1024);
#pragma unroll
    for (int i = 0; i < 4; ++i) pb[i] = *(const bf16x8*)(Bb + (size_t)(i * 8 + r8) * 1024);

#pragma unroll
    for (int s = 0; s < 4; ++s) {
#pragma unroll
        for (int i = 0; i < 8; ++i) *(bf16x8*)&As[(i * 8 + r8) * 72 + kb * 8] = pa[i];
#pragma unroll
        for (int i = 0; i < 4; ++i) *(bf16x8*)&Bs[(i * 8 + r8) * 72 + kb * 8] = pb[i];
        if (s < 3) {   // issue next slice's loads; they fly under the MFMA below
            const int off = (s + 1) * 64;
#pragma unroll
            for (int i = 0; i < 8; ++i) pa[i] = *(const bf16x8*)(Ab + (size_t)(i * 8 + r8) * 1024 + off);
#pragma unroll
            for (int i = 0; i < 4; ++i) pb[i] = *(const bf16x8*)(Bb + (size_t)(i * 8 + r8) * 1024 + off);
        }
#pragma unroll
        for (int kh = 0; kh < 2; ++kh) {
            bf16x8 aF[4], bF[2];
#pragma unroll
            for (int i = 0; i < 4; ++i)
                aF[i] = *(const bf16x8*)&As[(i * 16 + fr) * 72 + kh * 32 + fk];
#pragma unroll
            for (int j = 0; j < 2; ++j)
                bF[j] = *(const bf16x8*)&Bs[(j * 16 + fr) * 72 + kh * 32 + fk];
#pragma unroll
            for (int i = 0; i < 4; ++i)
#pragma unroll
                for (int j = 0; j < 2; ++j)
                    acc[i][j] = __builtin_amdgcn_mfma_f32_16x16x32_bf16(aF[i], bF[j], acc[i][j], 0, 0, 0);
        }
    }

    __syncthreads();   // all waves done with staging; reuse LDS as Cr
    {
        float* Crw = Cr + w * 2304;
        const int orow = fq * 4;
#pragma unroll
        for (int i = 0; i < 4; ++i)
#pragma unroll
            for (int j = 0; j < 2; ++j)
#pragma unroll
                for (int rr = 0; rr < 4; ++rr)
                    Crw[(i * 16 + orow + rr) * 36 + j * 16 + fr] = acc[i][j][rr];
    }
    __syncthreads();

    const int cc = (t & 7) * 4;
    f32x4 bv4 = *(const f32x4*)&bias[n_base + cc];
#pragma unroll
    for (int it = 0; it < 2; ++it) {
        const int row = (t >> 3) + it * 32;
        f32x4 s0 = *(const f32x4*)&Cr[0 * 2304 + row * 36 + cc];
        f32x4 s1 = *(const f32x4*)&Cr[1 * 2304 + row * 36 + cc];
        f32x4 s2 = *(const f32x4*)&Cr[2 * 2304 + row * 36 + cc];
        f32x4 s3 = *(const f32x4*)&Cr[3 * 2304 + row * 36 + cc];
        f32x4 v = (s0 + s1) + (s2 + s3) + bv4;
        if (sp) {
            v[0] = softplus_f(v[0]); v[1] = softplus_f(v[1]);
            v[2] = softplus_f(v[2]); v[3] = softplus_f(v[3]);
        }
        *(f32x4*)&dst[(size_t)(m_base + row) * 1024 + n_base + cc] = v;
    }
}

// ---------------- feat: G[h][d=128][k=256] fp32 (transposed) + cvec[h][k] ----------------
__global__ __launch_bounds__(256) void feat_kernel(const float* __restrict__ Km,
                                                   const float* __restrict__ Kv,
                                                   float* __restrict__ G,
                                                   float* __restrict__ cvec) {
    const int h = blockIdx.x, kb = blockIdx.y;
    const int t = threadIdx.x;
    const int kx = t & 63;
    const int dg = t >> 6;
    const int k = kb * 64 + kx;
    const float* kvp = Kv + (size_t)k * 1024 + h * 64 + dg * 16;
    const float* kmp = Km + (size_t)k * 1024 + h * 64 + dg * 16;
    float* gbase = G + (size_t)h * 32768;
    float cp = 0.f;
#pragma unroll
    for (int c = 0; c < 4; ++c) {
        f32x4 kv = *(const f32x4*)(kvp + c * 4);
        f32x4 km = *(const f32x4*)(kmp + c * 4);
#pragma unroll
        for (int e = 0; e < 4; ++e) {
            const int d = dg * 16 + c * 4 + e;
            const float r = 0.5f * fast_rcp(kv[e]);
            gbase[(size_t)d * 256 + k]        = r;                    // g1
            gbase[(size_t)(64 + d) * 256 + k] = -2.f * km[e] * r;     // g2
            cp += km[e] * km[e] * r + 0.5f * __logf(kv[e]);
        }
    }
    __shared__ float red[4][64];
    red[dg][kx] = cp;
    __syncthreads();
    if (dg == 0)
        cvec[h * 256 + k] = red[0][kx] + red[1][kx] + red[2][kx] + red[3][kx];
}

// ---------------- attn_v4: 4 q-rows per wave, p^2 precomputed, b128 Sc reads ----------------
__global__ __launch_bounds__(128) void attn_v4(const float* __restrict__ Qm,
                                               const float* __restrict__ Qv,
                                               const float* __restrict__ G,
                                               const float* __restrict__ cvec,
                                               const float* __restrict__ Vm,
                                               const float* __restrict__ Vv,
                                               bf16_t* __restrict__ Omu,
                                               bf16_t* __restrict__ Ovar) {
    const int bq = blockIdx.x, h = blockIdx.y;   // 8 q rows per block
    const int t = threadIdx.x, w = t >> 6, lane = t & 63;
    const int q0 = bq * 8;
    const int fw = w * 4;
    const int qw = q0 + fw;

    __shared__ float Fs[8][128];
    __shared__ float Sc[8][260];
    __shared__ float Sc2[8][260];

    {   // stage F
        const int r = t >> 4, c = t & 15;
        const float* qmp = Qm + (size_t)(q0 + r) * 1024 + h * 64 + c * 4;
        const float* qvp = Qv + (size_t)(q0 + r) * 1024 + h * 64 + c * 4;
        f32x4 qm = *(const f32x4*)qmp;
        f32x4 qv = *(const f32x4*)qvp;
        *(f32x4*)&Fs[r][c * 4]      = qm * qm + qv;
        *(f32x4*)&Fs[r][64 + c * 4] = qm;
    }
    __syncthreads();

    // scores: one G load feeds 4 accumulator rows
    f32x4 acc0 = {0.f,0.f,0.f,0.f}, acc1 = acc0, acc2 = acc0, acc3 = acc0;
    const float* gp = G + (size_t)h * 32768 + lane * 4;
#pragma unroll 8
    for (int d = 0; d < 128; ++d) {
        f32x4 g = *(const f32x4*)(gp + (size_t)d * 256);
        acc0 += Fs[fw + 0][d] * g;
        acc1 += Fs[fw + 1][d] * g;
        acc2 += Fs[fw + 2][d] * g;
        acc3 += Fs[fw + 3][d] * g;
    }

    const f32x4 c4 = *(const f32x4*)&cvec[h * 256 + lane * 4];
    f32x4 sr[4];
    sr[0] = (acc0 + c4) * (-0.125f);
    sr[1] = (acc1 + c4) * (-0.125f);
    sr[2] = (acc2 + c4) * (-0.125f);
    sr[3] = (acc3 + c4) * (-0.125f);

#pragma unroll
    for (int r = 0; r < 4; ++r) {
        f32x4 s = sr[r];
        float mloc = fmaxf(fmaxf(s[0], s[1]), fmaxf(s[2], s[3]));
#pragma unroll
        for (int off = 32; off > 0; off >>= 1)
            mloc = fmaxf(mloc, __shfl_xor(mloc, off, 64));
        s[0] = __expf(s[0] - mloc); s[1] = __expf(s[1] - mloc);
        s[2] = __expf(s[2] - mloc); s[3] = __expf(s[3] - mloc);
        float sl = (s[0] + s[1]) + (s[2] + s[3]);
#pragma unroll
        for (int off = 32; off > 0; off >>= 1)
            sl += __shfl_xor(sl, off, 64);
        s *= fast_rcp(sl);
        *(f32x4*)&Sc[fw + r][lane * 4]  = s;
        *(f32x4*)&Sc2[fw + r][lane * 4] = s * s;
    }
    __syncthreads();

    // PV: b128 broadcast reads of Sc/Sc2, one vm/vv pair feeds 4 rows
    float am[4] = {0.f,0.f,0.f,0.f}, av[4] = {0.f,0.f,0.f,0.f};
    const float* vmp = Vm + h * 64 + lane;
    const float* vvp = Vv + h * 64 + lane;
#pragma unroll 4
    for (int k4 = 0; k4 < 256; k4 += 4) {
        f32x4 p0 = *(const f32x4*)&Sc[fw + 0][k4];
        f32x4 p1 = *(const f32x4*)&Sc[fw + 1][k4];
        f32x4 p2 = *(const f32x4*)&Sc[fw + 2][k4];
        f32x4 p3 = *(const f32x4*)&Sc[fw + 3][k4];
        f32x4 q0v = *(const f32x4*)&Sc2[fw + 0][k4];
        f32x4 q1v = *(const f32x4*)&Sc2[fw + 1][k4];
        f32x4 q2v = *(const f32x4*)&Sc2[fw + 2][k4];
        f32x4 q3v = *(const f32x4*)&Sc2[fw + 3][k4];
#pragma unroll
        for (int e = 0; e < 4; ++e) {
            const float vm = vmp[(size_t)(k4 + e) * 1024];
            const float vv = vvp[(size_t)(k4 + e) * 1024];
            am[0] += p0[e] * vm;  av[0] += q0v[e] * vv;
            am[1] += p1[e] * vm;  av[1] += q1v[e] * vv;
            am[2] += p2[e] * vm;  av[2] += q2v[e] * vv;
            am[3] += p3[e] * vm;  av[3] += q3v[e] * vv;
        }
    }
#pragma unroll
    for (int r = 0; r < 4; ++r) {
        const size_t ob = (size_t)(qw + r) * 1024 + h * 64 + lane;
        Omu[ob]  = (bf16_t)am[r];
        Ovar[ob] = (bf16_t)av[r];
    }
}

// ---------------- launch ----------------
extern "C" void kernel_launch(void* const* d_in, const int* in_sizes, int n_in,
                              void* d_out, int out_size, void* d_ws, size_t ws_size,
                              hipStream_t stream) {
    const float* mu  = (const float*)d_in[0];
    const float* var = (const float*)d_in[1];

    uint8_t* ws = (uint8_t*)d_ws;
    bf16_t* Abf_mu  = (bf16_t*)(ws);                              // 512 KB
    bf16_t* Abf_var = (bf16_t*)(ws + (512u << 10));               // 512 KB
    bf16_t* WtB     = (bf16_t*)(ws + (1u << 20));                 // 8 x 2 MB
    float*  Proj    = (float*)(ws + (17u << 20));                 // 6 x 1 MB: Qm,Qv,Km,Kv,Vm,Vv
    bf16_t* Obf_mu  = (bf16_t*)(ws + (23u << 20));                // 512 KB
    bf16_t* Obf_var = (bf16_t*)(ws + (23u << 20) + (512u << 10)); // 512 KB
    float*  G       = (float*)(ws + (24u << 20));                 // 2 MB: [16][128][256]
    float*  cvec    = (float*)(ws + (26u << 20));                 // 16 KB

    PrepArgs pa;
    for (int i = 0; i < 8; ++i) pa.src[i] = (const float*)d_in[2 + 2 * i];
    pa.mu = mu; pa.var = var;
    prep_kernel<<<dim3(16, 16, 9), 256, 0, stream>>>(pa, WtB, Abf_mu, Abf_var);

    GemmArgs g1;
    for (int z = 0; z < 6; ++z) {
        g1.A[z]    = (z & 1) ? Abf_var : Abf_mu;
        g1.Wt[z]   = WtB + (size_t)z * 1048576;
        g1.bias[z] = (const float*)d_in[3 + 2 * z];
        g1.dst[z]  = Proj + (size_t)z * 262144;
        g1.splus[z] = (z & 1);
    }
    gemm_splitk<<<dim3(32, 4, 6), 256, 0, stream>>>(g1);

    feat_kernel<<<dim3(16, 4), 256, 0, stream>>>(Proj + 2 * 262144, Proj + 3 * 262144, G, cvec);

    attn_v4<<<dim3(32, 16), 128, 0, stream>>>(Proj,
                                              Proj + 262144,
                                              G, cvec,
                                              Proj + 4 * 262144,
                                              Proj + 5 * 262144,
                                              Obf_mu, Obf_var);

    GemmArgs g3;
    for (int z = 0; z < 6; ++z) {
        g3.A[z]    = Obf_mu;
        g3.Wt[z]   = WtB + (size_t)6 * 1048576;
        g3.bias[z] = (const float*)d_in[15];
        g3.dst[z]  = (float*)d_out;
        g3.splus[z] = 0;
    }
    g3.A[1]    = Obf_var;
    g3.Wt[1]   = WtB + (size_t)7 * 1048576;
    g3.bias[1] = (const float*)d_in[17];
    g3.dst[1]  = (float*)d_out + 262144;
    g3.splus[1] = 1;
    gemm_splitk<<<dim3(32, 4, 2), 256, 0, stream>>>(g3);
}

// Round 7
// 153.011 us; speedup vs baseline: 1.1501x; 1.1501x over previous
//
#include <hip/hip_runtime.h>
#include <math.h>

typedef __bf16 bf16_t;
typedef bf16_t bf16x4 __attribute__((ext_vector_type(4)));
typedef bf16_t bf16x8 __attribute__((ext_vector_type(8)));
typedef float  f32x4  __attribute__((ext_vector_type(4)));

__device__ __forceinline__ float softplus_f(float x) {
    return (x > 20.f) ? x : log1pf(expf(x));
}

__device__ __forceinline__ float fast_rcp(float x) {
#if __has_builtin(__builtin_amdgcn_rcpf)
    return __builtin_amdgcn_rcpf(x);
#else
    return 1.0f / x;
#endif
}

// ---------------- prep: z<8 transpose+convert weights, z==8 convert activations ----------------
struct PrepArgs { const float* src[8]; const float* mu; const float* var; };

__global__ __launch_bounds__(256) void prep_kernel(PrepArgs pa, bf16_t* __restrict__ wtbase,
                                                   bf16_t* __restrict__ dmu, bf16_t* __restrict__ dvar) {
    const int t = threadIdx.x;
    if (blockIdx.z == 8) {
        const int gid = (blockIdx.y * 16 + blockIdx.x) * 256 + t;   // 0..65535
        const float* s; bf16_t* d; int off;
        if (gid < 32768) { s = pa.mu;  d = dmu;  off = gid * 8; }
        else             { s = pa.var; d = dvar; off = (gid - 32768) * 8; }
        float4 v0 = *(const float4*)(s + off);
        float4 v1 = *(const float4*)(s + off + 4);
        bf16x8 o;
        o[0] = (bf16_t)v0.x; o[1] = (bf16_t)v0.y; o[2] = (bf16_t)v0.z; o[3] = (bf16_t)v0.w;
        o[4] = (bf16_t)v1.x; o[5] = (bf16_t)v1.y; o[6] = (bf16_t)v1.z; o[7] = (bf16_t)v1.w;
        *(bf16x8*)(d + off) = o;
        return;
    }
    const int kt = blockIdx.x, nt = blockIdx.y, wm = blockIdx.z;
    const float* __restrict__ W = pa.src[wm];
    bf16_t* __restrict__ Wt = wtbase + (size_t)wm * 1048576;
    __shared__ bf16_t Ts[64][72];
    const int r0 = t >> 4, c4 = (t & 15) * 4;
#pragma unroll
    for (int rep = 0; rep < 4; ++rep) {
        const int r = r0 + rep * 16;
        const float4 v = *(const float4*)&W[(size_t)(kt * 64 + r) * 1024 + nt * 64 + c4];
        Ts[c4 + 0][r] = (bf16_t)v.x;
        Ts[c4 + 1][r] = (bf16_t)v.y;
        Ts[c4 + 2][r] = (bf16_t)v.z;
        Ts[c4 + 3][r] = (bf16_t)v.w;
    }
    __syncthreads();
#pragma unroll
    for (int rep = 0; rep < 2; ++rep) {
        const int chunk = t + rep * 256;
        const int n = chunk >> 3, kc = (chunk & 7) * 8;
        bf16x8 v = *(const bf16x8*)&Ts[n][kc];
        *(bf16x8*)&Wt[(size_t)(nt * 64 + n) * 1024 + kt * 64 + kc] = v;
    }
}

// ---------------- gemm: 64x64 tile, intra-block split-K (R5 known-good) ----------------
struct GemmArgs {
    const bf16_t* A[6];
    const bf16_t* Wt[6];
    const float*  bias[6];
    float*        dst[6];
    int           splus[6];
};

__global__ __launch_bounds__(256, 2) void gemm_splitk(GemmArgs args) {
    const int z = blockIdx.z;
    const bf16_t* __restrict__ A    = args.A[z];
    const bf16_t* __restrict__ Wt   = args.Wt[z];
    const float*  __restrict__ bias = args.bias[z];
    float*        __restrict__ dst  = args.dst[z];
    const int sp = args.splus[z];

    const int n_base = blockIdx.x * 64;
    const int m_base = blockIdx.y * 64;

    __shared__ __align__(16) unsigned char smem_raw[73728];
    bf16_t* stage = (bf16_t*)smem_raw;
    float*  Cr    = (float*)smem_raw;

    const int t = threadIdx.x;
    const int lane = t & 63;
    const int w = t >> 6;
    bf16_t* As = stage + w * 9216;
    bf16_t* Bs = As + 4608;

    const int r8 = lane >> 3, kb = lane & 7;
    const int fr = lane & 15, fq = lane >> 4, fk = fq * 8;

    f32x4 acc[4][4] = {};

#pragma unroll
    for (int s = 0; s < 4; ++s) {
        const int k0 = w * 256 + s * 64;
#pragma unroll
        for (int i = 0; i < 8; ++i) {
            const int row = i * 8 + r8;
            bf16x8 av = *(const bf16x8*)&A [(size_t)(m_base + row) * 1024 + k0 + kb * 8];
            bf16x8 bv = *(const bf16x8*)&Wt[(size_t)(n_base + row) * 1024 + k0 + kb * 8];
            *(bf16x8*)&As[row * 72 + kb * 8] = av;
            *(bf16x8*)&Bs[row * 72 + kb * 8] = bv;
        }
#pragma unroll
        for (int kh = 0; kh < 2; ++kh) {
            bf16x8 aF[4], bF[4];
#pragma unroll
            for (int i = 0; i < 4; ++i)
                aF[i] = *(const bf16x8*)&As[(i * 16 + fr) * 72 + kh * 32 + fk];
#pragma unroll
            for (int j = 0; j < 4; ++j)
                bF[j] = *(const bf16x8*)&Bs[(j * 16 + fr) * 72 + kh * 32 + fk];
#pragma unroll
            for (int i = 0; i < 4; ++i)
#pragma unroll
                for (int j = 0; j < 4; ++j)
                    acc[i][j] = __builtin_amdgcn_mfma_f32_16x16x32_bf16(aF[i], bF[j], acc[i][j], 0, 0, 0);
        }
    }

    __syncthreads();
    {
        float* Crw = Cr + w * 4352;
        const int orow = fq * 4;
#pragma unroll
        for (int i = 0; i < 4; ++i)
#pragma unroll
            for (int j = 0; j < 4; ++j)
#pragma unroll
                for (int rr = 0; rr < 4; ++rr)
                    Crw[(i * 16 + orow + rr) * 68 + j * 16 + fr] = acc[i][j][rr];
    }
    __syncthreads();

    const int cc = (t & 15) * 4;
    f32x4 bv4 = *(const f32x4*)&bias[n_base + cc];
#pragma unroll
    for (int i = 0; i < 4; ++i) {
        const int row = (t >> 4) + i * 16;
        f32x4 s0 = *(const f32x4*)&Cr[0 * 4352 + row * 68 + cc];
        f32x4 s1 = *(const f32x4*)&Cr[1 * 4352 + row * 68 + cc];
        f32x4 s2 = *(const f32x4*)&Cr[2 * 4352 + row * 68 + cc];
        f32x4 s3 = *(const f32x4*)&Cr[3 * 4352 + row * 68 + cc];
        f32x4 v = (s0 + s1) + (s2 + s3) + bv4;
        if (sp) {
            v[0] = softplus_f(v[0]); v[1] = softplus_f(v[1]);
            v[2] = softplus_f(v[2]); v[3] = softplus_f(v[3]);
        }
        *(f32x4*)&dst[(size_t)(m_base + row) * 1024 + n_base + cc] = v;
    }
}

// ---------------- feat: G[h][d=128][k=256] fp32 (transposed) + cvec[h][k] ----------------
__global__ __launch_bounds__(256) void feat_kernel(const float* __restrict__ Km,
                                                   const float* __restrict__ Kv,
                                                   float* __restrict__ G,
                                                   float* __restrict__ cvec) {
    const int h = blockIdx.x, kb = blockIdx.y;
    const int t = threadIdx.x;
    const int kx = t & 63;
    const int dg = t >> 6;
    const int k = kb * 64 + kx;
    const float* kvp = Kv + (size_t)k * 1024 + h * 64 + dg * 16;
    const float* kmp = Km + (size_t)k * 1024 + h * 64 + dg * 16;
    float* gbase = G + (size_t)h * 32768;
    float cp = 0.f;
#pragma unroll
    for (int c = 0; c < 4; ++c) {
        f32x4 kv = *(const f32x4*)(kvp + c * 4);
        f32x4 km = *(const f32x4*)(kmp + c * 4);
#pragma unroll
        for (int e = 0; e < 4; ++e) {
            const int d = dg * 16 + c * 4 + e;
            const float r = 0.5f * fast_rcp(kv[e]);
            gbase[(size_t)d * 256 + k]        = r;
            gbase[(size_t)(64 + d) * 256 + k] = -2.f * km[e] * r;
            cp += km[e] * km[e] * r + 0.5f * __logf(kv[e]);
        }
    }
    __shared__ float red[4][64];
    red[dg][kx] = cp;
    __syncthreads();
    if (dg == 0)
        cvec[h * 256 + k] = red[0][kx] + red[1][kx] + red[2][kx] + red[3][kx];
}

// ---------------- attn_v5: LDS-fed scores + MFMA PV ----------------
// block = (qt:16 q rows, h). 256 thr / 4 waves. 1 block/CU (105 KB LDS).
// LDS: Vsm[256][72]bf16 | Vsv[256][72]bf16 | union{ Gs[16][260]f32 + Fs[16][132]f32 ,
//      Phi/Plo/P2hi/P2lo [16][264]bf16 }
#define OFF_VM   0
#define OFF_VV   36864
#define OFF_GS   73728
#define OFF_FS   90368
#define OFF_PHI  73728
#define OFF_PLO  82176
#define OFF_P2HI 90624
#define OFF_P2LO 99072
#define ATTN_SMEM 107520

__global__ __launch_bounds__(256) void attn_v5(const float* __restrict__ Qm,
                                               const float* __restrict__ Qv,
                                               const float* __restrict__ G,
                                               const float* __restrict__ cvec,
                                               const float* __restrict__ Vm,
                                               const float* __restrict__ Vv,
                                               bf16_t* __restrict__ Omu,
                                               bf16_t* __restrict__ Ovar) {
    __shared__ __align__(16) unsigned char smem[ATTN_SMEM];
    bf16_t* Vsm = (bf16_t*)(smem + OFF_VM);
    bf16_t* Vsv = (bf16_t*)(smem + OFF_VV);
    float*  Gs  = (float*)(smem + OFF_GS);
    float*  Fs  = (float*)(smem + OFF_FS);
    bf16_t* Phi = (bf16_t*)(smem + OFF_PHI);
    bf16_t* Plo = (bf16_t*)(smem + OFF_PLO);
    bf16_t* P2h = (bf16_t*)(smem + OFF_P2HI);
    bf16_t* P2l = (bf16_t*)(smem + OFF_P2LO);

    const int qt = blockIdx.x, h = blockIdx.y;
    const int t = threadIdx.x, w = t >> 6, lane = t & 63;
    const int fr = lane & 15, fq = lane >> 4;
    const int fw = w * 4;            // wave's 4 q rows (local)

    // ---- stage F (16 rows x 128 d) ----
    {
        const int r = t >> 4, c = t & 15;
        f32x4 qm = *(const f32x4*)(Qm + (size_t)(qt * 16 + r) * 1024 + h * 64 + c * 4);
        f32x4 qv = *(const f32x4*)(Qv + (size_t)(qt * 16 + r) * 1024 + h * 64 + c * 4);
        *(f32x4*)&Fs[r * 132 + c * 4]      = qm * qm + qv;
        *(f32x4*)&Fs[r * 132 + 64 + c * 4] = qm;
    }

    // ---- stage G chunk 0 ----
    const float* gsrc = G + (size_t)h * 32768 + (size_t)(t >> 4) * 256 + (t & 15) * 16;
    {
        f32x4 g0 = *(const f32x4*)(gsrc);
        f32x4 g1 = *(const f32x4*)(gsrc + 4);
        f32x4 g2 = *(const f32x4*)(gsrc + 8);
        f32x4 g3 = *(const f32x4*)(gsrc + 12);
        float* gd = &Gs[(t >> 4) * 260 + (t & 15) * 16];
        *(f32x4*)(gd)      = g0;
        *(f32x4*)(gd + 4)  = g1;
        *(f32x4*)(gd + 8)  = g2;
        *(f32x4*)(gd + 12) = g3;
    }
    __syncthreads();

    // ---- score loop: 8 chunks of 16 d; V staged in units interleaved ----
    f32x4 acc0 = {0.f,0.f,0.f,0.f}, acc1 = acc0, acc2 = acc0, acc3 = acc0;
    const int vk = t >> 2, vpart = t & 3;   // V staging map: 64 k rows x 4 dh-groups

    for (int c = 0; c < 8; ++c) {
        // prefetch next G chunk into registers
        f32x4 g0, g1, g2, g3;
        if (c < 7) {
            const float* s = gsrc + (size_t)(c + 1) * 4096;
            g0 = *(const f32x4*)(s);
            g1 = *(const f32x4*)(s + 4);
            g2 = *(const f32x4*)(s + 8);
            g3 = *(const f32x4*)(s + 12);
        }
        // V unit c: mat = c>>2 (0=Vm,1=Vv), rep = c&3
        const int rep = c & 3;
        const int kkv = vk + rep * 64;
        const float* vsrc = ((c >> 2) ? Vv : Vm) + (size_t)kkv * 1024 + h * 64 + vpart * 16;
        f32x4 v0 = *(const f32x4*)(vsrc);
        f32x4 v1 = *(const f32x4*)(vsrc + 4);
        f32x4 v2 = *(const f32x4*)(vsrc + 8);
        f32x4 v3 = *(const f32x4*)(vsrc + 12);

        // compute chunk c
#pragma unroll
        for (int dl = 0; dl < 16; ++dl) {
            f32x4 g = *(const f32x4*)&Gs[dl * 260 + lane * 4];
            const int d = c * 16 + dl;
            acc0 += Fs[(fw + 0) * 132 + d] * g;
            acc1 += Fs[(fw + 1) * 132 + d] * g;
            acc2 += Fs[(fw + 2) * 132 + d] * g;
            acc3 += Fs[(fw + 3) * 132 + d] * g;
        }
        __syncthreads();   // all waves done reading Gs chunk c
        {   // write V unit c to LDS (bf16)
            bf16_t* vdst = ((c >> 2) ? Vsv : Vsm) + kkv * 72 + vpart * 16;
            bf16x8 o0, o1;
            o0[0]=(bf16_t)v0[0]; o0[1]=(bf16_t)v0[1]; o0[2]=(bf16_t)v0[2]; o0[3]=(bf16_t)v0[3];
            o0[4]=(bf16_t)v1[0]; o0[5]=(bf16_t)v1[1]; o0[6]=(bf16_t)v1[2]; o0[7]=(bf16_t)v1[3];
            o1[0]=(bf16_t)v2[0]; o1[1]=(bf16_t)v2[1]; o1[2]=(bf16_t)v2[2]; o1[3]=(bf16_t)v2[3];
            o1[4]=(bf16_t)v3[0]; o1[5]=(bf16_t)v3[1]; o1[6]=(bf16_t)v3[2]; o1[7]=(bf16_t)v3[3];
            *(bf16x8*)(vdst)     = o0;
            *(bf16x8*)(vdst + 8) = o1;
        }
        if (c < 7) {
            float* gd = &Gs[(t >> 4) * 260 + (t & 15) * 16];
            *(f32x4*)(gd)      = g0;
            *(f32x4*)(gd + 4)  = g1;
            *(f32x4*)(gd + 8)  = g2;
            *(f32x4*)(gd + 12) = g3;
        }
        __syncthreads();   // Gs writes visible for chunk c+1
    }

    // ---- softmax (per q row, wave-local) ----
    const f32x4 c4 = *(const f32x4*)&cvec[h * 256 + lane * 4];
    f32x4 sr[4];
    sr[0] = (acc0 + c4) * (-0.125f);
    sr[1] = (acc1 + c4) * (-0.125f);
    sr[2] = (acc2 + c4) * (-0.125f);
    sr[3] = (acc3 + c4) * (-0.125f);

#pragma unroll
    for (int r = 0; r < 4; ++r) {
        f32x4 s = sr[r];
        float mloc = fmaxf(fmaxf(s[0], s[1]), fmaxf(s[2], s[3]));
#pragma unroll
        for (int off = 32; off > 0; off >>= 1)
            mloc = fmaxf(mloc, __shfl_xor(mloc, off, 64));
        s[0] = __expf(s[0] - mloc); s[1] = __expf(s[1] - mloc);
        s[2] = __expf(s[2] - mloc); s[3] = __expf(s[3] - mloc);
        float sl = (s[0] + s[1]) + (s[2] + s[3]);
#pragma unroll
        for (int off = 32; off > 0; off >>= 1)
            sl += __shfl_xor(sl, off, 64);
        sr[r] = s * fast_rcp(sl);
    }

    // ---- stage P hi/lo + P^2 hi/lo (aliases Gs/Fs region; all reads of Gs done) ----
#pragma unroll
    for (int r = 0; r < 4; ++r) {
        bf16x4 phi, plo, p2hi, p2lo;
#pragma unroll
        for (int e = 0; e < 4; ++e) {
            const float p = sr[r][e];
            const bf16_t hb = (bf16_t)p;
            phi[e] = hb; plo[e] = (bf16_t)(p - (float)hb);
            const float p2 = p * p;
            const bf16_t h2 = (bf16_t)p2;
            p2hi[e] = h2; p2lo[e] = (bf16_t)(p2 - (float)h2);
        }
        const int row = fw + r;
        *(bf16x4*)&Phi[row * 264 + lane * 4] = phi;
        *(bf16x4*)&Plo[row * 264 + lane * 4] = plo;
        *(bf16x4*)&P2h[row * 264 + lane * 4] = p2hi;
        *(bf16x4*)&P2l[row * 264 + lane * 4] = p2lo;
    }
    __syncthreads();

    // ---- PV via MFMA: wave w owns dh tile [w*16, w*16+16) ----
    f32x4 accm = {0.f,0.f,0.f,0.f}, accv = {0.f,0.f,0.f,0.f};
#pragma unroll
    for (int k0 = 0; k0 < 256; k0 += 32) {
        const int ka = k0 + fq * 8;
        bf16x8 ahi = *(const bf16x8*)&Phi[fr * 264 + ka];
        bf16x8 alo = *(const bf16x8*)&Plo[fr * 264 + ka];
        bf16x8 a2h = *(const bf16x8*)&P2h[fr * 264 + ka];
        bf16x8 a2l = *(const bf16x8*)&P2l[fr * 264 + ka];
        bf16x8 bm, bv;
#pragma unroll
        for (int j = 0; j < 8; ++j) {
            const int kk = ka + j;
            bm[j] = Vsm[kk * 72 + w * 16 + fr];
            bv[j] = Vsv[kk * 72 + w * 16 + fr];
        }
        accm = __builtin_amdgcn_mfma_f32_16x16x32_bf16(ahi, bm, accm, 0, 0, 0);
        accm = __builtin_amdgcn_mfma_f32_16x16x32_bf16(alo, bm, accm, 0, 0, 0);
        accv = __builtin_amdgcn_mfma_f32_16x16x32_bf16(a2h, bv, accv, 0, 0, 0);
        accv = __builtin_amdgcn_mfma_f32_16x16x32_bf16(a2l, bv, accv, 0, 0, 0);
    }

    // ---- epilogue: C layout row=(lane>>4)*4+reg (q), col=lane&15 (dh in tile) ----
#pragma unroll
    for (int reg = 0; reg < 4; ++reg) {
        const int qg = qt * 16 + fq * 4 + reg;
        const size_t ob = (size_t)qg * 1024 + h * 64 + w * 16 + fr;
        Omu[ob]  = (bf16_t)accm[reg];
        Ovar[ob] = (bf16_t)accv[reg];
    }
}

// ---------------- launch ----------------
extern "C" void kernel_launch(void* const* d_in, const int* in_sizes, int n_in,
                              void* d_out, int out_size, void* d_ws, size_t ws_size,
                              hipStream_t stream) {
    const float* mu  = (const float*)d_in[0];
    const float* var = (const float*)d_in[1];

    uint8_t* ws = (uint8_t*)d_ws;
    bf16_t* Abf_mu  = (bf16_t*)(ws);                              // 512 KB
    bf16_t* Abf_var = (bf16_t*)(ws + (512u << 10));               // 512 KB
    bf16_t* WtB     = (bf16_t*)(ws + (1u << 20));                 // 8 x 2 MB
    float*  Proj    = (float*)(ws + (17u << 20));                 // 6 x 1 MB: Qm,Qv,Km,Kv,Vm,Vv
    bf16_t* Obf_mu  = (bf16_t*)(ws + (23u << 20));                // 512 KB
    bf16_t* Obf_var = (bf16_t*)(ws + (23u << 20) + (512u << 10)); // 512 KB
    float*  G       = (float*)(ws + (24u << 20));                 // 2 MB: [16][128][256]
    float*  cvec    = (float*)(ws + (26u << 20));                 // 16 KB

    PrepArgs pa;
    for (int i = 0; i < 8; ++i) pa.src[i] = (const float*)d_in[2 + 2 * i];
    pa.mu = mu; pa.var = var;
    prep_kernel<<<dim3(16, 16, 9), 256, 0, stream>>>(pa, WtB, Abf_mu, Abf_var);

    GemmArgs g1;
    for (int z = 0; z < 6; ++z) {
        g1.A[z]    = (z & 1) ? Abf_var : Abf_mu;
        g1.Wt[z]   = WtB + (size_t)z * 1048576;
        g1.bias[z] = (const float*)d_in[3 + 2 * z];
        g1.dst[z]  = Proj + (size_t)z * 262144;
        g1.splus[z] = (z & 1);
    }
    gemm_splitk<<<dim3(16, 4, 6), 256, 0, stream>>>(g1);

    feat_kernel<<<dim3(16, 4), 256, 0, stream>>>(Proj + 2 * 262144, Proj + 3 * 262144, G, cvec);

    attn_v5<<<dim3(16, 16), 256, 0, stream>>>(Proj,
                                              Proj + 262144,
                                              G, cvec,
                                              Proj + 4 * 262144,
                                              Proj + 5 * 262144,
                                              Obf_mu, Obf_var);

    GemmArgs g3;
    for (int z = 0; z < 6; ++z) {
        g3.A[z]    = Obf_mu;
        g3.Wt[z]   = WtB + (size_t)6 * 1048576;
        g3.bias[z] = (const float*)d_in[15];
        g3.dst[z]  = (float*)d_out;
        g3.splus[z] = 0;
    }
    g3.A[1]    = Obf_var;
    g3.Wt[1]   = WtB + (size_t)7 * 1048576;
    g3.bias[1] = (const float*)d_in[17];
    g3.dst[1]  = (float*)d_out + 262144;
    g3.splus[1] = 1;
    gemm_splitk<<<dim3(16, 4, 2), 256, 0, stream>>>(g3);
}

// Round 8
// 150.909 us; speedup vs baseline: 1.1661x; 1.0139x over previous
//
#include <hip/hip_runtime.h>
#include <math.h>

typedef __bf16 bf16_t;
typedef bf16_t bf16x4 __attribute__((ext_vector_type(4)));
typedef bf16_t bf16x8 __attribute__((ext_vector_type(8)));
typedef float  f32x4  __attribute__((ext_vector_type(4)));

__device__ __forceinline__ float softplus_f(float x) {
    return (x > 20.f) ? x : log1pf(expf(x));
}

__device__ __forceinline__ float fast_rcp(float x) {
#if __has_builtin(__builtin_amdgcn_rcpf)
    return __builtin_amdgcn_rcpf(x);
#else
    return 1.0f / x;
#endif
}

// ---------------- prep: z<8 transpose+convert weights, z==8 convert activations ----------------
struct PrepArgs { const float* src[8]; const float* mu; const float* var; };

__global__ __launch_bounds__(256) void prep_kernel(PrepArgs pa, bf16_t* __restrict__ wtbase,
                                                   bf16_t* __restrict__ dmu, bf16_t* __restrict__ dvar) {
    const int t = threadIdx.x;
    if (blockIdx.z == 8) {
        const int gid = (blockIdx.y * 16 + blockIdx.x) * 256 + t;   // 0..65535
        const float* s; bf16_t* d; int off;
        if (gid < 32768) { s = pa.mu;  d = dmu;  off = gid * 8; }
        else             { s = pa.var; d = dvar; off = (gid - 32768) * 8; }
        float4 v0 = *(const float4*)(s + off);
        float4 v1 = *(const float4*)(s + off + 4);
        bf16x8 o;
        o[0] = (bf16_t)v0.x; o[1] = (bf16_t)v0.y; o[2] = (bf16_t)v0.z; o[3] = (bf16_t)v0.w;
        o[4] = (bf16_t)v1.x; o[5] = (bf16_t)v1.y; o[6] = (bf16_t)v1.z; o[7] = (bf16_t)v1.w;
        *(bf16x8*)(d + off) = o;
        return;
    }
    const int kt = blockIdx.x, nt = blockIdx.y, wm = blockIdx.z;
    const float* __restrict__ W = pa.src[wm];
    bf16_t* __restrict__ Wt = wtbase + (size_t)wm * 1048576;
    __shared__ bf16_t Ts[64][72];
    const int r0 = t >> 4, c4 = (t & 15) * 4;
#pragma unroll
    for (int rep = 0; rep < 4; ++rep) {
        const int r = r0 + rep * 16;
        const float4 v = *(const float4*)&W[(size_t)(kt * 64 + r) * 1024 + nt * 64 + c4];
        Ts[c4 + 0][r] = (bf16_t)v.x;
        Ts[c4 + 1][r] = (bf16_t)v.y;
        Ts[c4 + 2][r] = (bf16_t)v.z;
        Ts[c4 + 3][r] = (bf16_t)v.w;
    }
    __syncthreads();
#pragma unroll
    for (int rep = 0; rep < 2; ++rep) {
        const int chunk = t + rep * 256;
        const int n = chunk >> 3, kc = (chunk & 7) * 8;
        bf16x8 v = *(const bf16x8*)&Ts[n][kc];
        *(bf16x8*)&Wt[(size_t)(nt * 64 + n) * 1024 + kt * 64 + kc] = v;
    }
}

// ---------------- gemm: 64x64 tile, intra-block split-K (R5 known-good) ----------------
struct GemmArgs {
    const bf16_t* A[6];
    const bf16_t* Wt[6];
    const float*  bias[6];
    float*        dst[6];
    int           splus[6];
};

__global__ __launch_bounds__(256, 2) void gemm_splitk(GemmArgs args) {
    const int z = blockIdx.z;
    const bf16_t* __restrict__ A    = args.A[z];
    const bf16_t* __restrict__ Wt   = args.Wt[z];
    const float*  __restrict__ bias = args.bias[z];
    float*        __restrict__ dst  = args.dst[z];
    const int sp = args.splus[z];

    const int n_base = blockIdx.x * 64;
    const int m_base = blockIdx.y * 64;

    __shared__ __align__(16) unsigned char smem_raw[73728];
    bf16_t* stage = (bf16_t*)smem_raw;
    float*  Cr    = (float*)smem_raw;

    const int t = threadIdx.x;
    const int lane = t & 63;
    const int w = t >> 6;
    bf16_t* As = stage + w * 9216;
    bf16_t* Bs = As + 4608;

    const int r8 = lane >> 3, kb = lane & 7;
    const int fr = lane & 15, fq = lane >> 4, fk = fq * 8;

    f32x4 acc[4][4] = {};

#pragma unroll
    for (int s = 0; s < 4; ++s) {
        const int k0 = w * 256 + s * 64;
#pragma unroll
        for (int i = 0; i < 8; ++i) {
            const int row = i * 8 + r8;
            bf16x8 av = *(const bf16x8*)&A [(size_t)(m_base + row) * 1024 + k0 + kb * 8];
            bf16x8 bv = *(const bf16x8*)&Wt[(size_t)(n_base + row) * 1024 + k0 + kb * 8];
            *(bf16x8*)&As[row * 72 + kb * 8] = av;
            *(bf16x8*)&Bs[row * 72 + kb * 8] = bv;
        }
#pragma unroll
        for (int kh = 0; kh < 2; ++kh) {
            bf16x8 aF[4], bF[4];
#pragma unroll
            for (int i = 0; i < 4; ++i)
                aF[i] = *(const bf16x8*)&As[(i * 16 + fr) * 72 + kh * 32 + fk];
#pragma unroll
            for (int j = 0; j < 4; ++j)
                bF[j] = *(const bf16x8*)&Bs[(j * 16 + fr) * 72 + kh * 32 + fk];
#pragma unroll
            for (int i = 0; i < 4; ++i)
#pragma unroll
                for (int j = 0; j < 4; ++j)
                    acc[i][j] = __builtin_amdgcn_mfma_f32_16x16x32_bf16(aF[i], bF[j], acc[i][j], 0, 0, 0);
        }
    }

    __syncthreads();
    {
        float* Crw = Cr + w * 4352;
        const int orow = fq * 4;
#pragma unroll
        for (int i = 0; i < 4; ++i)
#pragma unroll
            for (int j = 0; j < 4; ++j)
#pragma unroll
                for (int rr = 0; rr < 4; ++rr)
                    Crw[(i * 16 + orow + rr) * 68 + j * 16 + fr] = acc[i][j][rr];
    }
    __syncthreads();

    const int cc = (t & 15) * 4;
    f32x4 bv4 = *(const f32x4*)&bias[n_base + cc];
#pragma unroll
    for (int i = 0; i < 4; ++i) {
        const int row = (t >> 4) + i * 16;
        f32x4 s0 = *(const f32x4*)&Cr[0 * 4352 + row * 68 + cc];
        f32x4 s1 = *(const f32x4*)&Cr[1 * 4352 + row * 68 + cc];
        f32x4 s2 = *(const f32x4*)&Cr[2 * 4352 + row * 68 + cc];
        f32x4 s3 = *(const f32x4*)&Cr[3 * 4352 + row * 68 + cc];
        f32x4 v = (s0 + s1) + (s2 + s3) + bv4;
        if (sp) {
            v[0] = softplus_f(v[0]); v[1] = softplus_f(v[1]);
            v[2] = softplus_f(v[2]); v[3] = softplus_f(v[3]);
        }
        *(f32x4*)&dst[(size_t)(m_base + row) * 1024 + n_base + cc] = v;
    }
}

// ---------------- feat: Gbf[h][katt=256][d=128] bf16 (MFMA B-layout) + cvec[h][katt] ----------------
// d<64: g1 = 0.5/Kv ; d>=64: g2 = -Km/Kv ; c(katt) = sum_d Km^2/(2Kv) + 0.5*log(Kv)
__global__ __launch_bounds__(256) void feat_kernel(const float* __restrict__ Km,
                                                   const float* __restrict__ Kv,
                                                   bf16_t* __restrict__ Gbf,
                                                   float* __restrict__ cvec) {
    const int h = blockIdx.x, kb = blockIdx.y;
    const int t = threadIdx.x;
    const int kx = t & 63;
    const int dg = t >> 6;
    const int katt = kb * 64 + kx;
    const float* kvp = Kv + (size_t)katt * 1024 + h * 64 + dg * 16;
    const float* kmp = Km + (size_t)katt * 1024 + h * 64 + dg * 16;
    bf16_t* grow = Gbf + ((size_t)(h * 256 + katt)) * 128;
    float cp = 0.f;
#pragma unroll
    for (int c = 0; c < 4; ++c) {
        f32x4 kv = *(const f32x4*)(kvp + c * 4);
        f32x4 km = *(const f32x4*)(kmp + c * 4);
        bf16x4 o1, o2;
#pragma unroll
        for (int e = 0; e < 4; ++e) {
            const float r = 0.5f * fast_rcp(kv[e]);
            o1[e] = (bf16_t)r;
            o2[e] = (bf16_t)(-2.f * km[e] * r);
            cp += km[e] * km[e] * r + 0.5f * __logf(kv[e]);
        }
        *(bf16x4*)&grow[dg * 16 + c * 4]      = o1;
        *(bf16x4*)&grow[64 + dg * 16 + c * 4] = o2;
    }
    __shared__ float red[4][64];
    red[dg][kx] = cp;
    __syncthreads();
    if (dg == 0)
        cvec[h * 256 + katt] = red[0][kx] + red[1][kx] + red[2][kx] + red[3][kx];
}

// ---------------- attn_v6: MFMA scores + MFMA PV ----------------
// block (qt, h), 256 thr / 4 waves, grid 256 = 1 block/CU.
// wave w owns katt slice [w*64, w*64+64) for scores, dh tile [w*16,+16) for PV.
#define OFF_VM   0
#define OFF_VV   36864
#define OFF_FS   73728
#define OFF_SC   82176
#define OFF_PHI  98816
#define OFF_PLO  107264
#define OFF_P2H  115712
#define OFF_P2L  124160
#define ATTN_SMEM 132608

__global__ __launch_bounds__(256) void attn_v6(const float* __restrict__ Qm,
                                               const float* __restrict__ Qv,
                                               const bf16_t* __restrict__ Gbf,
                                               const float* __restrict__ cvec,
                                               const float* __restrict__ Vm,
                                               const float* __restrict__ Vv,
                                               bf16_t* __restrict__ Omu,
                                               bf16_t* __restrict__ Ovar) {
    __shared__ __align__(16) unsigned char smem[ATTN_SMEM];
    bf16_t* Vsm = (bf16_t*)(smem + OFF_VM);   // [256][72] bf16
    bf16_t* Vsv = (bf16_t*)(smem + OFF_VV);
    float*  Fs  = (float*)(smem + OFF_FS);    // [16][132] f32
    float*  Sc  = (float*)(smem + OFF_SC);    // [16][260] f32 (scaled logits)
    bf16_t* Phi = (bf16_t*)(smem + OFF_PHI);  // [16][264] bf16
    bf16_t* Plo = (bf16_t*)(smem + OFF_PLO);
    bf16_t* P2h = (bf16_t*)(smem + OFF_P2H);
    bf16_t* P2l = (bf16_t*)(smem + OFF_P2L);

    const int qt = blockIdx.x, h = blockIdx.y;
    const int t = threadIdx.x, w = t >> 6, lane = t & 63;
    const int fr = lane & 15, fq = lane >> 4;
    const int n0 = w * 64;

    // B-frag base: Gbf[h][n0+fr + nt*16][fq*8 + ks*32]
    const bf16_t* gB = Gbf + ((size_t)(h * 256 + n0 + fr)) * 128 + fq * 8;

    // prefetch B frags for nt=0
    bf16x8 bcur[4];
#pragma unroll
    for (int ks = 0; ks < 4; ++ks) bcur[ks] = *(const bf16x8*)(gB + ks * 32);

    // stage F (fp32)
    {
        const int r = t >> 4, c = t & 15;
        f32x4 qm = *(const f32x4*)(Qm + (size_t)(qt * 16 + r) * 1024 + h * 64 + c * 4);
        f32x4 qv = *(const f32x4*)(Qv + (size_t)(qt * 16 + r) * 1024 + h * 64 + c * 4);
        *(f32x4*)&Fs[r * 132 + c * 4]      = qm * qm + qv;
        *(f32x4*)&Fs[r * 132 + 64 + c * 4] = qm;
    }
    __syncthreads();

    // A-frags hi/lo from Fs: A[q=fr][d = ks*32 + fq*8 + j]
    bf16x8 ahi[4], alo[4];
#pragma unroll
    for (int ks = 0; ks < 4; ++ks) {
        f32x4 f0 = *(const f32x4*)&Fs[fr * 132 + ks * 32 + fq * 8];
        f32x4 f1 = *(const f32x4*)&Fs[fr * 132 + ks * 32 + fq * 8 + 4];
#pragma unroll
        for (int e = 0; e < 4; ++e) {
            bf16_t hb = (bf16_t)f0[e];
            ahi[ks][e] = hb; alo[ks][e] = (bf16_t)(f0[e] - (float)hb);
            bf16_t hb2 = (bf16_t)f1[e];
            ahi[ks][e + 4] = hb2; alo[ks][e + 4] = (bf16_t)(f1[e] - (float)hb2);
        }
    }

    // score n-tiles with interleaved V staging (2 units per tile, 8 total)
    const int vk = t >> 2, vpart = t & 3;
#pragma unroll
    for (int nt = 0; nt < 4; ++nt) {
        // V units 2nt, 2nt+1:  u<4 -> Vm rep u, else Vv rep u-4
        const int ua = 2 * nt, ub = 2 * nt + 1;
        const float* vsa = ((ua >> 2) ? Vv : Vm) + (size_t)(vk + (ua & 3) * 64) * 1024 + h * 64 + vpart * 16;
        const float* vsb = ((ub >> 2) ? Vv : Vm) + (size_t)(vk + (ub & 3) * 64) * 1024 + h * 64 + vpart * 16;
        f32x4 va0 = *(const f32x4*)(vsa),     va1 = *(const f32x4*)(vsa + 4);
        f32x4 va2 = *(const f32x4*)(vsa + 8), va3 = *(const f32x4*)(vsa + 12);
        f32x4 vb0 = *(const f32x4*)(vsb),     vb1 = *(const f32x4*)(vsb + 4);
        f32x4 vb2 = *(const f32x4*)(vsb + 8), vb3 = *(const f32x4*)(vsb + 12);

        bf16x8 bnxt[4];
        if (nt < 3) {
#pragma unroll
            for (int ks = 0; ks < 4; ++ks)
                bnxt[ks] = *(const bf16x8*)(gB + (size_t)(nt + 1) * 2048 + ks * 32);
        }

        f32x4 acc = {0.f, 0.f, 0.f, 0.f};
#pragma unroll
        for (int ks = 0; ks < 4; ++ks) {
            acc = __builtin_amdgcn_mfma_f32_16x16x32_bf16(ahi[ks], bcur[ks], acc, 0, 0, 0);
            acc = __builtin_amdgcn_mfma_f32_16x16x32_bf16(alo[ks], bcur[ks], acc, 0, 0, 0);
        }

        {   // write V units to LDS bf16
            bf16_t* da = ((ua >> 2) ? Vsv : Vsm) + (vk + (ua & 3) * 64) * 72 + vpart * 16;
            bf16_t* db = ((ub >> 2) ? Vsv : Vsm) + (vk + (ub & 3) * 64) * 72 + vpart * 16;
            bf16x8 o0, o1;
            o0[0]=(bf16_t)va0[0]; o0[1]=(bf16_t)va0[1]; o0[2]=(bf16_t)va0[2]; o0[3]=(bf16_t)va0[3];
            o0[4]=(bf16_t)va1[0]; o0[5]=(bf16_t)va1[1]; o0[6]=(bf16_t)va1[2]; o0[7]=(bf16_t)va1[3];
            o1[0]=(bf16_t)va2[0]; o1[1]=(bf16_t)va2[1]; o1[2]=(bf16_t)va2[2]; o1[3]=(bf16_t)va2[3];
            o1[4]=(bf16_t)va3[0]; o1[5]=(bf16_t)va3[1]; o1[6]=(bf16_t)va3[2]; o1[7]=(bf16_t)va3[3];
            *(bf16x8*)(da)     = o0;
            *(bf16x8*)(da + 8) = o1;
            o0[0]=(bf16_t)vb0[0]; o0[1]=(bf16_t)vb0[1]; o0[2]=(bf16_t)vb0[2]; o0[3]=(bf16_t)vb0[3];
            o0[4]=(bf16_t)vb1[0]; o0[5]=(bf16_t)vb1[1]; o0[6]=(bf16_t)vb1[2]; o0[7]=(bf16_t)vb1[3];
            o1[0]=(bf16_t)vb2[0]; o1[1]=(bf16_t)vb2[1]; o1[2]=(bf16_t)vb2[2]; o1[3]=(bf16_t)vb2[3];
            o1[4]=(bf16_t)vb3[0]; o1[5]=(bf16_t)vb3[1]; o1[6]=(bf16_t)vb3[2]; o1[7]=(bf16_t)vb3[3];
            *(bf16x8*)(db)     = o0;
            *(bf16x8*)(db + 8) = o1;
        }

        // scaled logits -> Sc (C layout: row q = fq*4+reg, col katt = n0+nt*16+fr)
        const float cv = cvec[h * 256 + n0 + nt * 16 + fr];
        f32x4 lg = (acc + cv) * (-0.125f);
#pragma unroll
        for (int reg = 0; reg < 4; ++reg)
            Sc[(fq * 4 + reg) * 260 + n0 + nt * 16 + fr] = lg[reg];

#pragma unroll
        for (int ks = 0; ks < 4; ++ks) bcur[ks] = bnxt[ks];
    }
    __syncthreads();

    // ---- softmax (v5-verified): wave w owns q rows fw..fw+3, lane holds katt=lane*4..+3 ----
    const int fw = w * 4;
    f32x4 sr[4];
#pragma unroll
    for (int r = 0; r < 4; ++r)
        sr[r] = *(const f32x4*)&Sc[(fw + r) * 260 + lane * 4];
#pragma unroll
    for (int r = 0; r < 4; ++r) {
        f32x4 s = sr[r];
        float mloc = fmaxf(fmaxf(s[0], s[1]), fmaxf(s[2], s[3]));
#pragma unroll
        for (int off = 32; off > 0; off >>= 1)
            mloc = fmaxf(mloc, __shfl_xor(mloc, off, 64));
        s[0] = __expf(s[0] - mloc); s[1] = __expf(s[1] - mloc);
        s[2] = __expf(s[2] - mloc); s[3] = __expf(s[3] - mloc);
        float sl = (s[0] + s[1]) + (s[2] + s[3]);
#pragma unroll
        for (int off = 32; off > 0; off >>= 1)
            sl += __shfl_xor(sl, off, 64);
        sr[r] = s * fast_rcp(sl);
    }

    // ---- stage P hi/lo + P^2 hi/lo ----
#pragma unroll
    for (int r = 0; r < 4; ++r) {
        bf16x4 phi, plo, p2hi, p2lo;
#pragma unroll
        for (int e = 0; e < 4; ++e) {
            const float p = sr[r][e];
            const bf16_t hb = (bf16_t)p;
            phi[e] = hb; plo[e] = (bf16_t)(p - (float)hb);
            const float p2 = p * p;
            const bf16_t h2 = (bf16_t)p2;
            p2hi[e] = h2; p2lo[e] = (bf16_t)(p2 - (float)h2);
        }
        const int row = fw + r;
        *(bf16x4*)&Phi[row * 264 + lane * 4] = phi;
        *(bf16x4*)&Plo[row * 264 + lane * 4] = plo;
        *(bf16x4*)&P2h[row * 264 + lane * 4] = p2hi;
        *(bf16x4*)&P2l[row * 264 + lane * 4] = p2lo;
    }
    __syncthreads();

    // ---- PV via MFMA: wave w owns dh tile [w*16, w*16+16) ----
    f32x4 accm = {0.f,0.f,0.f,0.f}, accv = {0.f,0.f,0.f,0.f};
#pragma unroll
    for (int k0 = 0; k0 < 256; k0 += 32) {
        const int ka = k0 + fq * 8;
        bf16x8 ahi2 = *(const bf16x8*)&Phi[fr * 264 + ka];
        bf16x8 alo2 = *(const bf16x8*)&Plo[fr * 264 + ka];
        bf16x8 a2h  = *(const bf16x8*)&P2h[fr * 264 + ka];
        bf16x8 a2l  = *(const bf16x8*)&P2l[fr * 264 + ka];
        bf16x8 bm, bv;
#pragma unroll
        for (int j = 0; j < 8; ++j) {
            const int kk = ka + j;
            bm[j] = Vsm[kk * 72 + w * 16 + fr];
            bv[j] = Vsv[kk * 72 + w * 16 + fr];
        }
        accm = __builtin_amdgcn_mfma_f32_16x16x32_bf16(ahi2, bm, accm, 0, 0, 0);
        accm = __builtin_amdgcn_mfma_f32_16x16x32_bf16(alo2, bm, accm, 0, 0, 0);
        accv = __builtin_amdgcn_mfma_f32_16x16x32_bf16(a2h,  bv, accv, 0, 0, 0);
        accv = __builtin_amdgcn_mfma_f32_16x16x32_bf16(a2l,  bv, accv, 0, 0, 0);
    }

#pragma unroll
    for (int reg = 0; reg < 4; ++reg) {
        const int qg = qt * 16 + fq * 4 + reg;
        const size_t ob = (size_t)qg * 1024 + h * 64 + w * 16 + fr;
        Omu[ob]  = (bf16_t)accm[reg];
        Ovar[ob] = (bf16_t)accv[reg];
    }
}

// ---------------- launch ----------------
extern "C" void kernel_launch(void* const* d_in, const int* in_sizes, int n_in,
                              void* d_out, int out_size, void* d_ws, size_t ws_size,
                              hipStream_t stream) {
    const float* mu  = (const float*)d_in[0];
    const float* var = (const float*)d_in[1];

    uint8_t* ws = (uint8_t*)d_ws;
    bf16_t* Abf_mu  = (bf16_t*)(ws);                              // 512 KB
    bf16_t* Abf_var = (bf16_t*)(ws + (512u << 10));               // 512 KB
    bf16_t* WtB     = (bf16_t*)(ws + (1u << 20));                 // 8 x 2 MB
    float*  Proj    = (float*)(ws + (17u << 20));                 // 6 x 1 MB
    bf16_t* Obf_mu  = (bf16_t*)(ws + (23u << 20));                // 512 KB
    bf16_t* Obf_var = (bf16_t*)(ws + (23u << 20) + (512u << 10)); // 512 KB
    bf16_t* Gbf     = (bf16_t*)(ws + (24u << 20));                // 1 MB: [16][256][128] bf16
    float*  cvec    = (float*)(ws + (25u << 20));                 // 16 KB

    PrepArgs pa;
    for (int i = 0; i < 8; ++i) pa.src[i] = (const float*)d_in[2 + 2 * i];
    pa.mu = mu; pa.var = var;
    prep_kernel<<<dim3(16, 16, 9), 256, 0, stream>>>(pa, WtB, Abf_mu, Abf_var);

    GemmArgs g1;
    for (int z = 0; z < 6; ++z) {
        g1.A[z]    = (z & 1) ? Abf_var : Abf_mu;
        g1.Wt[z]   = WtB + (size_t)z * 1048576;
        g1.bias[z] = (const float*)d_in[3 + 2 * z];
        g1.dst[z]  = Proj + (size_t)z * 262144;
        g1.splus[z] = (z & 1);
    }
    gemm_splitk<<<dim3(16, 4, 6), 256, 0, stream>>>(g1);

    feat_kernel<<<dim3(16, 4), 256, 0, stream>>>(Proj + 2 * 262144, Proj + 3 * 262144, Gbf, cvec);

    attn_v6<<<dim3(16, 16), 256, 0, stream>>>(Proj,
                                              Proj + 262144,
                                              Gbf, cvec,
                                              Proj + 4 * 262144,
                                              Proj + 5 * 262144,
                                              Obf_mu, Obf_var);

    GemmArgs g3;
    for (int z = 0; z < 6; ++z) {
        g3.A[z]    = Obf_mu;
        g3.Wt[z]   = WtB + (size_t)6 * 1048576;
        g3.bias[z] = (const float*)d_in[15];
        g3.dst[z]  = (float*)d_out;
        g3.splus[z] = 0;
    }
    g3.A[1]    = Obf_var;
    g3.Wt[1]   = WtB + (size_t)7 * 1048576;
    g3.bias[1] = (const float*)d_in[17];
    g3.dst[1]  = (float*)d_out + 262144;
    g3.splus[1] = 1;
    gemm_splitk<<<dim3(16, 4, 2), 256, 0, stream>>>(g3);
}